// Round 18
// baseline (1074.067 us; speedup 1.0000x reference)
//
#include <hip/hip_runtime.h>
#include <hip/hip_bf16.h>

#define DIM    512
#define HEADS  8
#define DHD    64
#define MLAND  256
#define NTOK   10001
#define NPATCH 10000
#define NPAD   10240
#define PADR   239
#define LFAC   40
#define MOUT   10112
#define NSPLIT 8

typedef __bf16 bf16x8_t __attribute__((ext_vector_type(8)));
typedef float  f32x4_t  __attribute__((ext_vector_type(4)));
typedef short  short8_t __attribute__((ext_vector_type(8)));

__device__ inline bf16x8_t bzero8() {
    union { short8_t s; bf16x8_t b; } u;
    u.s = (short8_t){0, 0, 0, 0, 0, 0, 0, 0};
    return u.b;
}

#define GLDS(gp, lp) __builtin_amdgcn_global_load_lds( \
    (const __attribute__((address_space(1))) void*)(gp), \
    (__attribute__((address_space(3))) void*)(lp), 16, 0, 0)

// ---------------------------------------------------------------- concat
__global__ void k_concat(const float* __restrict__ x, const float* __restrict__ cls,
                         float* __restrict__ h) {
    int idx = blockIdx.x * 256 + threadIdx.x;
    if (idx >= NTOK * DIM) return;
    int row = idx / DIM, col = idx % DIM;
    h[idx] = (row == 0) ? cls[col] : x[(row - 1) * DIM + col];
}

// ---------------------------------------------------------------- layernorm -> bf16 padded A
__global__ void k_layernorm_bf(const float* __restrict__ h, const float* __restrict__ w,
                               const float* __restrict__ b, __hip_bfloat16* __restrict__ xbf) {
    int row = blockIdx.x;
    const float* r = h + (long)row * DIM;
    int t = threadIdx.x;
    float v0 = r[t], v1 = r[t + 256];
    __shared__ float red[256];
    red[t] = v0 + v1; __syncthreads();
    for (int o = 128; o > 0; o >>= 1) { if (t < o) red[t] += red[t + o]; __syncthreads(); }
    float mu = red[0] * (1.f / DIM); __syncthreads();
    float d0 = v0 - mu, d1 = v1 - mu;
    red[t] = d0 * d0 + d1 * d1; __syncthreads();
    for (int o = 128; o > 0; o >>= 1) { if (t < o) red[t] += red[t + o]; __syncthreads(); }
    float rstd = rsqrtf(red[0] * (1.f / DIM) + 1e-5f);
    long base = (long)(PADR + row) * DIM;
    xbf[base + t]       = __float2bfloat16(d0 * rstd * w[t] + b[t]);
    xbf[base + t + 256] = __float2bfloat16(d1 * rstd * w[t + 256] + b[t + 256]);
}

// ---------------------------------------------------------------- helpers
__global__ void k_zerobf(__hip_bfloat16* __restrict__ p, int n) {
    int i = blockIdx.x * 256 + threadIdx.x;
    if (i < n) p[i] = __float2bfloat16(0.f);
}
__global__ void k_wt_cvt(const float* __restrict__ W, __hip_bfloat16* __restrict__ Wt,
                         int K, int N) {
    __shared__ float tile[32][33];
    int k0 = blockIdx.x * 32, n0 = blockIdx.y * 32;
    int lx = threadIdx.x % 32, ly = threadIdx.x / 32;
    for (int i = 0; i < 32; i += 8) tile[ly + i][lx] = W[(long)(k0 + ly + i) * N + n0 + lx];
    __syncthreads();
    for (int i = 0; i < 32; i += 8)
        Wt[(long)(n0 + ly + i) * K + k0 + lx] = __float2bfloat16(tile[lx][ly + i]);
}
// vh [h][n][d] -> vt [h][d][n]
__global__ void k_vt(const __hip_bfloat16* __restrict__ vh, __hip_bfloat16* __restrict__ vt) {
    __shared__ __hip_bfloat16 tile[32][33];
    int n0 = blockIdx.x * 32, d0 = blockIdx.y * 32, h = blockIdx.z;
    int lx = threadIdx.x % 32, ly = threadIdx.x / 32;
    for (int i = 0; i < 32; i += 8)
        tile[ly + i][lx] = vh[((long)h * NPAD + n0 + ly + i) * 64 + d0 + lx];
    __syncthreads();
    for (int i = 0; i < 32; i += 8)
        vt[((long)h * 64 + d0 + ly + i) * NPAD + n0 + lx] = tile[lx][ly + i];
}

// ---------------------------------------------------------------- qkv GEMM 128x128 BK=64, global_load_lds staging
__global__ __launch_bounds__(256) void k_qkv_gemm(
    const __hip_bfloat16* __restrict__ A, const __hip_bfloat16* __restrict__ Bt,
    __hip_bfloat16* __restrict__ qh, __hip_bfloat16* __restrict__ kh,
    __hip_bfloat16* __restrict__ vh)
{
    const int K = 512;
    __shared__ unsigned short As[128 * 64];
    __shared__ unsigned short Bs[128 * 64];
    int tid = threadIdx.x;
    int m0 = blockIdx.y * 128, n0 = blockIdx.x * 128;
    int wave = tid >> 6, lane = tid & 63;
    int wm = (wave & 1) * 64, wn = (wave >> 1) * 64;
    f32x4_t zero4 = {0.f, 0.f, 0.f, 0.f};
    f32x4_t acc[4][4];
#pragma unroll
    for (int i = 0; i < 4; i++)
#pragma unroll
        for (int j = 0; j < 4; j++) acc[i][j] = zero4;
    int quad = lane >> 4, fr = lane & 15;
    int lrow8 = lane >> 3, gls = lane & 7;
    int gg = gls ^ lrow8;

    for (int k0 = 0; k0 < K; k0 += 64) {
        __syncthreads();
#pragma unroll
        for (int rnd = 0; rnd < 4; rnd++) {
            int r0 = rnd * 32 + wave * 8;
            int ar = r0 + lrow8;
            GLDS(A  + (long)(m0 + ar) * K + k0 + gg * 8, &As[r0 * 64]);
            GLDS(Bt + (long)(n0 + ar) * K + k0 + gg * 8, &Bs[r0 * 64]);
        }
        __syncthreads();
#pragma unroll
        for (int ks = 0; ks < 2; ks++) {
            int sg = (ks * 4 + quad) ^ (fr & 7);
            bf16x8_t af[4], bq[4];
#pragma unroll
            for (int i = 0; i < 4; i++) {
                af[i] = *(const bf16x8_t*)&As[(wm + i * 16 + fr) * 64 + sg * 8];
                bq[i] = *(const bf16x8_t*)&Bs[(wn + i * 16 + fr) * 64 + sg * 8];
            }
#pragma unroll
            for (int i = 0; i < 4; i++)
#pragma unroll
                for (int j = 0; j < 4; j++)
                    acc[i][j] = __builtin_amdgcn_mfma_f32_16x16x32_bf16(af[i], bq[j], acc[i][j], 0, 0, 0);
        }
    }
    int col = lane & 15, rq = lane >> 4;
#pragma unroll
    for (int j = 0; j < 4; j++) {
        int c = n0 + wn + j * 16 + col;
        int sect = c >> 9;          // 0=q 1=k 2=v
        int hh = (c >> 6) & 7;
        int d = c & 63;
        __hip_bfloat16* dst = (sect == 0) ? qh : (sect == 1) ? kh : vh;
        float sc = (sect == 0) ? 0.125f : 1.f;
#pragma unroll
        for (int i = 0; i < 4; i++) {
            int rbase = m0 + wm + i * 16 + rq * 4;
#pragma unroll
            for (int rr = 0; rr < 4; rr++) {
                int r = rbase + rr;
                dst[((long)hh * NPAD + r) * 64 + d] = __float2bfloat16(acc[i][j][rr] * sc);
            }
        }
    }
}

// ---------------------------------------------------------------- out-proj GEMM 128x128 BK=64, global_load_lds staging
__global__ __launch_bounds__(256) void k_mfma_gemm(
    const __hip_bfloat16* __restrict__ A, const __hip_bfloat16* __restrict__ Bt,
    float* __restrict__ C, int M, int N, int K, int Mstore,
    const float* __restrict__ bias, int accum)
{
    __shared__ unsigned short As[128 * 64];
    __shared__ unsigned short Bs[128 * 64];
    int tid = threadIdx.x;
    int m0 = blockIdx.y * 128, n0 = blockIdx.x * 128;
    int wave = tid >> 6, lane = tid & 63;
    int wm = (wave & 1) * 64, wn = (wave >> 1) * 64;
    f32x4_t zero4 = {0.f, 0.f, 0.f, 0.f};
    f32x4_t acc[4][4];
#pragma unroll
    for (int i = 0; i < 4; i++)
#pragma unroll
        for (int j = 0; j < 4; j++) acc[i][j] = zero4;
    int quad = lane >> 4, fr = lane & 15;
    int lrow8 = lane >> 3, gls = lane & 7;
    int gg = gls ^ lrow8;

    for (int k0 = 0; k0 < K; k0 += 64) {
        __syncthreads();
#pragma unroll
        for (int rnd = 0; rnd < 4; rnd++) {
            int r0 = rnd * 32 + wave * 8;
            int ar = r0 + lrow8;
            GLDS(A  + (long)(m0 + ar) * K + k0 + gg * 8, &As[r0 * 64]);
            GLDS(Bt + (long)(n0 + ar) * K + k0 + gg * 8, &Bs[r0 * 64]);
        }
        __syncthreads();
#pragma unroll
        for (int ks = 0; ks < 2; ks++) {
            int sg = (ks * 4 + quad) ^ (fr & 7);
            bf16x8_t af[4], bq[4];
#pragma unroll
            for (int i = 0; i < 4; i++) {
                af[i] = *(const bf16x8_t*)&As[(wm + i * 16 + fr) * 64 + sg * 8];
                bq[i] = *(const bf16x8_t*)&Bs[(wn + i * 16 + fr) * 64 + sg * 8];
            }
#pragma unroll
            for (int i = 0; i < 4; i++)
#pragma unroll
                for (int j = 0; j < 4; j++)
                    acc[i][j] = __builtin_amdgcn_mfma_f32_16x16x32_bf16(af[i], bq[j], acc[i][j], 0, 0, 0);
        }
    }
    int col = lane & 15, rq = lane >> 4;
#pragma unroll
    for (int j = 0; j < 4; j++) {
        int c = n0 + wn + j * 16 + col;
        float bsv = bias ? bias[c] : 0.f;
#pragma unroll
        for (int i = 0; i < 4; i++) {
            int rbase = m0 + wm + i * 16 + rq * 4;
#pragma unroll
            for (int rr = 0; rr < 4; rr++) {
                int r = rbase + rr;
                if (r >= Mstore) continue;
                float v = acc[i][j][rr] + bsv;
                long off = (long)r * N + c;
                if (accum) C[off] += v; else C[off] = v;
            }
        }
    }
}

// ---------------------------------------------------------------- generic MFMA 128x64, bf16-T out (w2bt)
__global__ __launch_bounds__(256) void k_mfma_t64(
    const __hip_bfloat16* __restrict__ A, long lda, long abatch, int arowmax,
    const __hip_bfloat16* __restrict__ Bt, long ldb, long bbatch,
    __hip_bfloat16* __restrict__ Cbf, long ldc, long cbatch, int ksplit)
{
    int h = blockIdx.z;
    const __hip_bfloat16* Ab = A + (long)h * abatch;
    const __hip_bfloat16* Bb = Bt + (long)h * bbatch;
    int m0 = blockIdx.y * 128;
    int kbeg = blockIdx.x * ksplit, kend = kbeg + ksplit;
    int wave = threadIdx.x >> 6, lane = threadIdx.x & 63;
    int wm = (wave & 1) * 64, wn = (wave >> 1) * 32;
    int fr = lane & 15, quad = lane >> 4;
    f32x4_t zero4 = {0.f, 0.f, 0.f, 0.f};
    f32x4_t acc[4][2];
#pragma unroll
    for (int i = 0; i < 4; i++) { acc[i][0] = zero4; acc[i][1] = zero4; }
    for (int k0 = kbeg; k0 < kend; k0 += 32) {
        bf16x8_t bq[2];
#pragma unroll
        for (int j = 0; j < 2; j++)
            bq[j] = *(const bf16x8_t*)(Bb + (long)(wn + j * 16 + fr) * ldb + k0 + quad * 8);
#pragma unroll
        for (int i = 0; i < 4; i++) {
            int r = m0 + wm + i * 16 + fr;
            bf16x8_t af = (r < arowmax) ? *(const bf16x8_t*)(Ab + (long)r * lda + k0 + quad * 8)
                                        : bzero8();
#pragma unroll
            for (int j = 0; j < 2; j++)
                acc[i][j] = __builtin_amdgcn_mfma_f32_16x16x32_bf16(af, bq[j], acc[i][j], 0, 0, 0);
        }
    }
#pragma unroll
    for (int i = 0; i < 4; i++)
#pragma unroll
        for (int j = 0; j < 2; j++)
#pragma unroll
            for (int rr = 0; rr < 4; rr++) {
                int r = m0 + wm + i * 16 + quad * 4 + rr;
                int c = wn + j * 16 + fr;
                Cbf[(long)h * cbatch + (long)c * ldc + r] = __float2bfloat16(acc[i][j][rr]);
            }
}

// ---------------------------------------------------------------- pinv phase: C = s*(A@B) + acoef*Aadd, per head
// 32x32 tile, grid (8,8,HEADS) = 512 blocks -> 2 blocks/CU latency overlap
__global__ __launch_bounds__(256) void k_mm256(
    const __hip_bfloat16* __restrict__ Aa, const __hip_bfloat16* __restrict__ Bt,
    float s, float acoef, const __hip_bfloat16* __restrict__ Aadd,
    __hip_bfloat16* __restrict__ Ca, __hip_bfloat16* __restrict__ Ct)
{
    int hd = blockIdx.z;
    long hb = (long)hd * 65536;
    int m0 = blockIdx.y * 32, n0 = blockIdx.x * 32;
    int wave = threadIdx.x >> 6, lane = threadIdx.x & 63;
    int fr = lane & 15, quad = lane >> 4;
    int mrow = m0 + (wave & 1) * 16;
    int ncol = n0 + (wave >> 1) * 16;
    f32x4_t acc = {0.f, 0.f, 0.f, 0.f};
#pragma unroll
    for (int k0 = 0; k0 < 256; k0 += 32) {
        bf16x8_t af = *(const bf16x8_t*)(Aa + hb + (long)(mrow + fr) * 256 + k0 + quad * 8);
        bf16x8_t bq = *(const bf16x8_t*)(Bt + hb + (long)(ncol + fr) * 256 + k0 + quad * 8);
        acc = __builtin_amdgcn_mfma_f32_16x16x32_bf16(af, bq, acc, 0, 0, 0);
    }
#pragma unroll
    for (int rr = 0; rr < 4; rr++) {
        int r = mrow + quad * 4 + rr;
        int c = ncol + fr;
        float v = s * acc[rr];
        if (Aadd) v += acoef * __bfloat162float(Aadd[hb + (long)r * 256 + c]);
        __hip_bfloat16 bv = __float2bfloat16(v);
        if (Ca) Ca[hb + (long)r * 256 + c] = bv;
        if (Ct) Ct[hb + (long)c * 256 + r] = bv;
    }
}

// ---------------------------------------------------------------- flash attn3: split-N online softmax, partial O/m/l
__global__ __launch_bounds__(256) void k_attn3f(
    const __hip_bfloat16* __restrict__ qlbf, const __hip_bfloat16* __restrict__ kh,
    const __hip_bfloat16* __restrict__ vt, float* __restrict__ part)
{
    int ns = blockIdx.x, mt = blockIdx.y, h = blockIdx.z;
    int wave = threadIdx.x >> 6, lane = threadIdx.x & 63;
    int fr = lane & 15, quad = lane >> 4;
    __shared__ __hip_bfloat16 Pl[64 * 264];
    f32x4_t zero4 = {0.f, 0.f, 0.f, 0.f};
    bf16x8_t aq[2];
    {
        const __hip_bfloat16* qb = qlbf + (long)h * 16384 + (long)(mt * 64 + wave * 16 + fr) * 64;
        aq[0] = *(const bf16x8_t*)(qb + quad * 8);
        aq[1] = *(const bf16x8_t*)(qb + 32 + quad * 8);
    }
    f32x4_t O[4];
#pragma unroll
    for (int j = 0; j < 4; j++) O[j] = zero4;
    float mr[4] = {-1e30f, -1e30f, -1e30f, -1e30f};
    float lr[4] = {0.f, 0.f, 0.f, 0.f};
    const __hip_bfloat16* kb = kh + (long)h * NPAD * 64;
    const __hip_bfloat16* vb = vt + (long)h * 64 * NPAD;

    for (int nt = 0; nt < 5; nt++) {
        int n0 = ns * 1280 + nt * 256;
        f32x4_t s[16];
#pragma unroll
        for (int j = 0; j < 16; j++) s[j] = zero4;
#pragma unroll
        for (int j = 0; j < 16; j++) {
            const __hip_bfloat16* kr = kb + (long)(n0 + j * 16 + fr) * 64;
            bf16x8_t b0 = *(const bf16x8_t*)(kr + quad * 8);
            bf16x8_t b1 = *(const bf16x8_t*)(kr + 32 + quad * 8);
            s[j] = __builtin_amdgcn_mfma_f32_16x16x32_bf16(aq[0], b0, s[j], 0, 0, 0);
            s[j] = __builtin_amdgcn_mfma_f32_16x16x32_bf16(aq[1], b1, s[j], 0, 0, 0);
        }
        float tm[4] = {-1e30f, -1e30f, -1e30f, -1e30f};
#pragma unroll
        for (int j = 0; j < 16; j++)
#pragma unroll
            for (int rr = 0; rr < 4; rr++) tm[rr] = fmaxf(tm[rr], s[j][rr]);
#pragma unroll
        for (int rr = 0; rr < 4; rr++) {
#pragma unroll
            for (int o = 8; o > 0; o >>= 1) tm[rr] = fmaxf(tm[rr], __shfl_xor(tm[rr], o));
        }
        float alpha[4], ts[4];
#pragma unroll
        for (int rr = 0; rr < 4; rr++) {
            float mnew = fmaxf(mr[rr], tm[rr]);
            alpha[rr] = __expf(mr[rr] - mnew);
            mr[rr] = mnew;
            ts[rr] = 0.f;
        }
#pragma unroll
        for (int j = 0; j < 16; j++)
#pragma unroll
            for (int rr = 0; rr < 4; rr++) {
                float e = __expf(s[j][rr] - mr[rr]);
                s[j][rr] = e;
                ts[rr] += e;
            }
#pragma unroll
        for (int rr = 0; rr < 4; rr++) {
#pragma unroll
            for (int o = 8; o > 0; o >>= 1) ts[rr] += __shfl_xor(ts[rr], o);
            lr[rr] = lr[rr] * alpha[rr] + ts[rr];
        }
#pragma unroll
        for (int j = 0; j < 4; j++)
#pragma unroll
            for (int rr = 0; rr < 4; rr++) O[j][rr] *= alpha[rr];
        __syncthreads();
#pragma unroll
        for (int j = 0; j < 16; j++)
#pragma unroll
            for (int rr = 0; rr < 4; rr++)
                Pl[(wave * 16 + quad * 4 + rr) * 264 + j * 16 + fr] = __float2bfloat16(s[j][rr]);
        __syncthreads();
#pragma unroll
        for (int k0 = 0; k0 < 256; k0 += 32) {
            bf16x8_t af = *(const bf16x8_t*)&Pl[(wave * 16 + fr) * 264 + k0 + quad * 8];
#pragma unroll
            for (int j = 0; j < 4; j++) {
                bf16x8_t bq = *(const bf16x8_t*)(vb + (long)(j * 16 + fr) * NPAD + n0 + k0 + quad * 8);
                O[j] = __builtin_amdgcn_mfma_f32_16x16x32_bf16(af, bq, O[j], 0, 0, 0);
            }
        }
    }
    float* Ob = part + (long)((h * 4 + mt) * NSPLIT + ns) * 4224;
#pragma unroll
    for (int j = 0; j < 4; j++)
#pragma unroll
        for (int rr = 0; rr < 4; rr++)
            Ob[(wave * 16 + quad * 4 + rr) * 64 + j * 16 + fr] = O[j][rr];
    if (fr == 0) {
#pragma unroll
        for (int rr = 0; rr < 4; rr++) {
            Ob[4096 + wave * 16 + quad * 4 + rr] = mr[rr];
            Ob[4160 + wave * 16 + quad * 4 + rr] = lr[rr];
        }
    }
}

// ---------------------------------------------------------------- combine attn3 partials -> a3vt bf16 [h][64][256]
__global__ void k_a3comb(const float* __restrict__ part, __hip_bfloat16* __restrict__ a3vt) {
    int mt = blockIdx.x, h = blockIdx.y, t = threadIdx.x;
    int row = t >> 2, c0 = (t & 3) * 16;
    long base = (long)((h * 4 + mt) * NSPLIT) * 4224;
    float M = -1e30f;
    for (int s = 0; s < NSPLIT; s++) M = fmaxf(M, part[base + s * 4224 + 4096 + row]);
    float L = 0.f;
    float o[16];
#pragma unroll
    for (int c = 0; c < 16; c++) o[c] = 0.f;
    for (int s = 0; s < NSPLIT; s++) {
        const float* pb = part + base + (long)s * 4224;
        float w = __expf(pb[4096 + row] - M);
        L += pb[4160 + row] * w;
#pragma unroll
        for (int c = 0; c < 16; c++) o[c] += w * pb[row * 64 + c0 + c];
    }
    float invL = 1.f / L;
#pragma unroll
    for (int c = 0; c < 16; c++)
        a3vt[(long)h * 16384 + (long)(c0 + c) * 256 + mt * 64 + row] = __float2bfloat16(o[c] * invL);
}

// ---------------------------------------------------------------- conv residual -> convbf (bf16), x4 vectorized
__global__ void k_conv_res(const __hip_bfloat16* __restrict__ vh, const float* __restrict__ resw,
                           __hip_bfloat16* __restrict__ convbf) {
    int e4 = blockIdx.x * 256 + threadIdx.x;
    if (e4 >= NTOK * 128) return;
    int i = e4 >> 7;
    int c4 = (e4 & 127) * 4;
    int hh = c4 >> 6, d = c4 & 63;
    int n = PADR + i;
    const __hip_bfloat16* vb = vh + (long)hh * NPAD * 64 + d;
    float a0 = 0.f, a1 = 0.f, a2 = 0.f, a3 = 0.f;
#pragma unroll
    for (int t = 0; t < 33; t++) {
        int nn = n - 16 + t;
        if (nn < NPAD) {
            float w = resw[hh * 33 + t];
            uint2 pv = *(const uint2*)(vb + (long)nn * 64);
            __hip_bfloat16 vv[4];
            *(uint2*)vv = pv;
            a0 += w * __bfloat162float(vv[0]);
            a1 += w * __bfloat162float(vv[1]);
            a2 += w * __bfloat162float(vv[2]);
            a3 += w * __bfloat162float(vv[3]);
        }
    }
    __hip_bfloat16 o[4] = {__float2bfloat16(a0), __float2bfloat16(a1),
                           __float2bfloat16(a2), __float2bfloat16(a3)};
    *(uint2*)(convbf + (long)i * DIM + c4) = *(uint2*)o;
}

// ---------------------------------------------------------------- fused attn1: scores -> softmax -> P@w2 -> +convbf -> abf
__global__ __launch_bounds__(256) void k_attn1f(
    const __hip_bfloat16* __restrict__ qh, const __hip_bfloat16* __restrict__ klbf,
    const __hip_bfloat16* __restrict__ w2bt, const __hip_bfloat16* __restrict__ convbf,
    __hip_bfloat16* __restrict__ abf)
{
    int h = blockIdx.y;
    int i0 = blockIdx.x * 64;
    __shared__ __hip_bfloat16 Pl[64 * 264];
    int tid = threadIdx.x;
    int wave = tid >> 6, lane = tid & 63;
    int fr = lane & 15, quad = lane >> 4;
    const __hip_bfloat16* kb = klbf + (long)h * (MLAND * DHD);
    f32x4_t zero4 = {0.f, 0.f, 0.f, 0.f};
    float cpre[4][4];
#pragma unroll
    for (int j = 0; j < 4; j++)
#pragma unroll
        for (int rr = 0; rr < 4; rr++) {
            int r = i0 + wave * 16 + quad * 4 + rr;
            cpre[j][rr] = (r < NTOK)
                ? __bfloat162float(convbf[(long)r * DIM + h * DHD + j * 16 + fr]) : 0.f;
        }
    f32x4_t acc[16];
#pragma unroll
    for (int j = 0; j < 16; j++) acc[j] = zero4;
    int arow = i0 + wave * 16 + fr;
    const __hip_bfloat16* qrow = qh + ((long)h * NPAD + PADR + arow) * 64;
#pragma unroll
    for (int k0 = 0; k0 < 64; k0 += 32) {
        bf16x8_t af = (arow < NTOK) ? *(const bf16x8_t*)(qrow + k0 + quad * 8) : bzero8();
#pragma unroll
        for (int j = 0; j < 16; j++) {
            bf16x8_t bq = *(const bf16x8_t*)(kb + (long)(j * 16 + fr) * DHD + k0 + quad * 8);
            acc[j] = __builtin_amdgcn_mfma_f32_16x16x32_bf16(af, bq, acc[j], 0, 0, 0);
        }
    }
    float mx[4] = {-1e30f, -1e30f, -1e30f, -1e30f};
#pragma unroll
    for (int j = 0; j < 16; j++)
#pragma unroll
        for (int rr = 0; rr < 4; rr++) mx[rr] = fmaxf(mx[rr], acc[j][rr]);
#pragma unroll
    for (int rr = 0; rr < 4; rr++) {
#pragma unroll
        for (int o = 8; o > 0; o >>= 1) mx[rr] = fmaxf(mx[rr], __shfl_xor(mx[rr], o));
    }
    float sum[4] = {0.f, 0.f, 0.f, 0.f};
#pragma unroll
    for (int j = 0; j < 16; j++)
#pragma unroll
        for (int rr = 0; rr < 4; rr++) {
            float e = __expf(acc[j][rr] - mx[rr]);
            acc[j][rr] = e;
            sum[rr] += e;
        }
#pragma unroll
    for (int rr = 0; rr < 4; rr++) {
#pragma unroll
        for (int o = 8; o > 0; o >>= 1) sum[rr] += __shfl_xor(sum[rr], o);
    }
#pragma unroll
    for (int j = 0; j < 16; j++)
#pragma unroll
        for (int rr = 0; rr < 4; rr++)
            Pl[(wave * 16 + quad * 4 + rr) * 264 + j * 16 + fr] =
                __float2bfloat16(acc[j][rr] / sum[rr]);
    __syncthreads();
    const __hip_bfloat16* wb = w2bt + (long)h * (DHD * MLAND);
    f32x4_t oc[4];
#pragma unroll
    for (int j = 0; j < 4; j++) oc[j] = zero4;
#pragma unroll
    for (int k0 = 0; k0 < 256; k0 += 32) {
        bf16x8_t af = *(const bf16x8_t*)&Pl[(wave * 16 + fr) * 264 + k0 + quad * 8];
#pragma unroll
        for (int j = 0; j < 4; j++) {
            bf16x8_t bq = *(const bf16x8_t*)(wb + (long)(j * 16 + fr) * MLAND + k0 + quad * 8);
            oc[j] = __builtin_amdgcn_mfma_f32_16x16x32_bf16(af, bq, oc[j], 0, 0, 0);
        }
    }
#pragma unroll
    for (int j = 0; j < 4; j++)
#pragma unroll
        for (int rr = 0; rr < 4; rr++) {
            int r = i0 + wave * 16 + quad * 4 + rr;
            if (r < NTOK) {
                long off = (long)r * DIM + h * DHD + j * 16 + fr;
                abf[off] = __float2bfloat16(cpre[j][rr] + oc[j][rr]);
            }
        }
}

// ---------------------------------------------------------------- landmark means (head-major in; fp32 + bf16 out)
__global__ void k_landmarks(const __hip_bfloat16* __restrict__ qh,
                            const __hip_bfloat16* __restrict__ kh,
                            float* __restrict__ ql, float* __restrict__ kl,
                            __hip_bfloat16* __restrict__ qlbf, __hip_bfloat16* __restrict__ klbf) {
    int m = blockIdx.x, h = blockIdx.y, d = threadIdx.x;
    float sq = 0.f, sk = 0.f;
    for (int j = 0; j < LFAC; j++) {
        long base = ((long)h * NPAD + m * LFAC + j) * 64 + d;
        sq += __bfloat162float(qh[base]);
        sk += __bfloat162float(kh[base]);
    }
    long o = ((long)h * MLAND + m) * DHD + d;
    float vq = sq * (1.f / LFAC), vk = sk * (1.f / LFAC);
    ql[o] = vq; kl[o] = vk;
    qlbf[o] = __float2bfloat16(vq);
    klbf[o] = __float2bfloat16(vk);
}

// ---------------------------------------------------------------- attn2 = softmax(q_l @ k_l^T), fp32 + bf16 out
__global__ void k_attn2(const float* __restrict__ ql, const float* __restrict__ kl,
                        float* __restrict__ attn2, __hip_bfloat16* __restrict__ attn2bf) {
    int i = blockIdx.x, h = blockIdx.y, j = threadIdx.x;
    __shared__ float q[64];
    __shared__ float red[256];
    if (j < 64) q[j] = ql[((long)h * MLAND + i) * DHD + j];
    __syncthreads();
    const float* kr = kl + ((long)h * MLAND + j) * DHD;
    float s = 0.f;
#pragma unroll 8
    for (int d = 0; d < 64; d++) s += q[d] * kr[d];
    red[j] = s; __syncthreads();
    for (int o = 128; o > 0; o >>= 1) { if (j < o) red[j] = fmaxf(red[j], red[j + o]); __syncthreads(); }
    float mx = red[0]; __syncthreads();
    float e = __expf(s - mx);
    red[j] = e; __syncthreads();
    for (int o = 128; o > 0; o >>= 1) { if (j < o) red[j] += red[j + o]; __syncthreads(); }
    float v = e / red[0];
    long off = ((long)h * MLAND + i) * MLAND + j;
    attn2[off] = v;
    attn2bf[off] = __float2bfloat16(v);
}

// ---------------------------------------------------------------- pinv scale: per-head col/row max sums (no atomics)
__global__ void k_colrow(const float* __restrict__ x, float* __restrict__ scal) {
    int h = blockIdx.x, t = threadIdx.x;
    const float* xh = x + (long)h * MLAND * MLAND;
    float cs = 0.f, rs = 0.f;
    for (int j = 0; j < MLAND; j++) {
        cs += fabsf(xh[(long)t * MLAND + j]);
        rs += fabsf(xh[(long)j * MLAND + t]);
    }
    __shared__ float red[256];
    red[t] = cs; __syncthreads();
    for (int o = 128; o > 0; o >>= 1) { if (t < o) red[t] = fmaxf(red[t], red[t + o]); __syncthreads(); }
    if (t == 0) scal[2 + h] = red[0];
    __syncthreads();
    red[t] = rs; __syncthreads();
    for (int o = 128; o > 0; o >>= 1) { if (t < o) red[t] = fmaxf(red[t], red[t + o]); __syncthreads(); }
    if (t == 0) scal[10 + h] = red[0];
}

// ---------------------------------------------------------------- z0 init (za = x^T*inv, zt = x*inv); global max inline
__global__ void k_tscale2(const float* __restrict__ x, const float* __restrict__ scal,
                          __hip_bfloat16* __restrict__ za, __hip_bfloat16* __restrict__ zt) {
    int h = blockIdx.z;
    int tj = blockIdx.x * 32, ti = blockIdx.y * 32;
    __shared__ float tile[32][33];
    const float* xh = x + (long)h * 65536;
    int lx = threadIdx.x % 32, ly = threadIdx.x / 32;
    float cm = scal[2], rm = scal[10];
#pragma unroll
    for (int k = 1; k < 8; k++) {
        cm = fmaxf(cm, scal[2 + k]);
        rm = fmaxf(rm, scal[10 + k]);
    }
    float inv = 1.f / (cm * rm);
    for (int yy = 0; yy < 32; yy += 8) {
        float v = xh[(long)(ti + ly + yy) * MLAND + tj + lx];
        tile[ly + yy][lx] = v;
        zt[(long)h * 65536 + (long)(ti + ly + yy) * MLAND + tj + lx] = __float2bfloat16(v * inv);
    }
    __syncthreads();
    for (int yy = 0; yy < 32; yy += 8)
        za[(long)h * 65536 + (long)(tj + ly + yy) * MLAND + ti + lx] =
            __float2bfloat16(tile[lx][ly + yy] * inv);
}

// ---------------------------------------------------------------- ppeg transposes + combined 49-tap conv
__global__ void k_tfwd(const float* __restrict__ h, float* __restrict__ ft) {
    __shared__ float tile[32][33];
    int t0 = blockIdx.x * 32, c0 = blockIdx.y * 32;
    int lx = threadIdx.x % 32, ly = threadIdx.x / 32;
    for (int i = 0; i < 32; i += 8) {
        int t = t0 + ly + i;
        if (t < NPATCH) tile[ly + i][lx] = h[(long)(1 + t) * DIM + c0 + lx];
    }
    __syncthreads();
    for (int i = 0; i < 32; i += 8) {
        int c = c0 + ly + i, t = t0 + lx;
        if (t < NPATCH) ft[(long)c * NPATCH + t] = tile[lx][ly + i];
    }
}

__global__ __launch_bounds__(256) void k_ppeg2(
    const float* __restrict__ ft, float* __restrict__ yt,
    const float* __restrict__ w7, const float* __restrict__ b7,
    const float* __restrict__ w5, const float* __restrict__ b5,
    const float* __restrict__ w3, const float* __restrict__ b3)
{
    int s = blockIdx.x, c = blockIdx.y;
    __shared__ float tile[26][106];
    __shared__ float wt[49];
    int tid = threadIdx.x;
    int r0 = s * 20 - 3;
    for (int idx = tid; idx < 26 * 106; idx += 256) {
        int rr = idx / 106, cc = idx % 106;
        int gy = r0 + rr, gx = cc - 3;
        float v = 0.f;
        if (gy >= 0 && gy < 100 && gx >= 0 && gx < 100)
            v = ft[(long)c * NPATCH + gy * 100 + gx];
        tile[rr][cc] = v;
    }
    if (tid < 49) {
        int dy = tid / 7 - 3, dx = tid % 7 - 3;
        float w = w7[c * 49 + tid];
        if (dy >= -2 && dy <= 2 && dx >= -2 && dx <= 2) w += w5[c * 25 + (dy + 2) * 5 + (dx + 2)];
        if (dy >= -1 && dy <= 1 && dx >= -1 && dx <= 1) w += w3[c * 9 + (dy + 1) * 3 + (dx + 1)];
        wt[tid] = w;
    }
    __syncthreads();
    float bsum = b7[c] + b5[c] + b3[c];
    for (int p = tid; p < 2000; p += 256) {
        int ly = p / 100, lx = p % 100;
        float acc = tile[ly + 3][lx + 3] + bsum;
#pragma unroll
        for (int dy = 0; dy < 7; dy++)
#pragma unroll
            for (int dx = 0; dx < 7; dx++)
                acc += wt[dy * 7 + dx] * tile[ly + dy][lx + dx];
        yt[(long)c * NPATCH + (s * 20 + ly) * 100 + lx] = acc;
    }
}

__global__ void k_tback(const float* __restrict__ yt, float* __restrict__ h) {
    __shared__ float tile[32][33];
    int t0 = blockIdx.x * 32, c0 = blockIdx.y * 32;
    int lx = threadIdx.x % 32, ly = threadIdx.x / 32;
    for (int i = 0; i < 32; i += 8) {
        int c = c0 + ly + i, t = t0 + lx;
        if (t < NPATCH) tile[ly + i][lx] = yt[(long)c * NPATCH + t];
    }
    __syncthreads();
    for (int i = 0; i < 32; i += 8) {
        int t = t0 + ly + i;
        if (t < NPATCH) h[(long)(1 + t) * DIM + c0 + lx] = tile[lx][ly + i];
    }
}

// ---------------------------------------------------------------- final LN + heads + softmax
__global__ void k_final(const float* __restrict__ h, const float* __restrict__ nw,
                        const float* __restrict__ nb,
                        const float* __restrict__ fc2w, const float* __restrict__ fc2b,
                        const float* __restrict__ pcw, const float* __restrict__ pcb,
                        float* __restrict__ out)
{
    int row = blockIdx.x;
    int t = threadIdx.x;
    const float* r = h + (long)row * DIM;
    float v0 = r[t], v1 = r[t + 256];
    __shared__ float red[256];
    red[t] = v0 + v1; __syncthreads();
    for (int o = 128; o > 0; o >>= 1) { if (t < o) red[t] += red[t + o]; __syncthreads(); }
    float mu = red[0] * (1.f / DIM); __syncthreads();
    float d0 = v0 - mu, d1 = v1 - mu;
    red[t] = d0 * d0 + d1 * d1; __syncthreads();
    for (int o = 128; o > 0; o >>= 1) { if (t < o) red[t] += red[t + o]; __syncthreads(); }
    float rstd = rsqrtf(red[0] * (1.f / DIM) + 1e-5f); __syncthreads();
    float h0 = d0 * rstd * nw[t] + nb[t];
    float h1 = d1 * rstd * nw[t + 256] + nb[t + 256];
    const float* w = (row == 0) ? fc2w : pcw;
    float p0 = h0 * w[t * 2] + h1 * w[(t + 256) * 2];
    float p1 = h0 * w[t * 2 + 1] + h1 * w[(t + 256) * 2 + 1];
    red[t] = p0; __syncthreads();
    for (int o = 128; o > 0; o >>= 1) { if (t < o) red[t] += red[t + o]; __syncthreads(); }
    float l0 = red[0]; __syncthreads();
    red[t] = p1; __syncthreads();
    for (int o = 128; o > 0; o >>= 1) { if (t < o) red[t] += red[t + o]; __syncthreads(); }
    if (t == 0) {
        float l1 = red[0];
        const float* bb = (row == 0) ? fc2b : pcb;
        float a0 = l0 + bb[0], a1 = l1 + bb[1];
        if (row == 0) { out[0] = a0; out[1] = a1; }
        else {
            long i = row - 1;
            out[2 + i * 2] = a0;
            out[2 + i * 2 + 1] = a1;
            float m = fmaxf(a0, a1);
            float e0 = __expf(a0 - m), e1 = __expf(a1 - m);
            float inv = 1.f / (e0 + e1);
            out[2 + 2 * NPATCH + i * 2] = e0 * inv;
            out[2 + 2 * NPATCH + i * 2 + 1] = e1 * inv;
        }
    }
}

// ================================================================ launcher
extern "C" void kernel_launch(void* const* d_in, const int* in_sizes, int n_in,
                              void* d_out, int out_size, void* d_ws, size_t ws_size,
                              hipStream_t stream)
{
    const float* x     = (const float*)d_in[0];
    const float* cls   = (const float*)d_in[1];
    const float* ln1w  = (const float*)d_in[2];
    const float* ln1b  = (const float*)d_in[3];
    const float* qkv1w = (const float*)d_in[4];
    const float* out1w = (const float*)d_in[5];
    const float* out1b = (const float*)d_in[6];
    const float* res1w = (const float*)d_in[7];
    const float* p7w   = (const float*)d_in[8];
    const float* p7b   = (const float*)d_in[9];
    const float* p5w   = (const float*)d_in[10];
    const float* p5b   = (const float*)d_in[11];
    const float* p3w   = (const float*)d_in[12];
    const float* p3b   = (const float*)d_in[13];
    const float* ln2w  = (const float*)d_in[14];
    const float* ln2b  = (const float*)d_in[15];
    const float* qkv2w = (const float*)d_in[16];
    const float* out2w = (const float*)d_in[17];
    const float* out2b = (const float*)d_in[18];
    const float* res2w = (const float*)d_in[19];
    const float* normw = (const float*)d_in[20];
    const float* normb = (const float*)d_in[21];
    const float* fc2w  = (const float*)d_in[22];
    const float* fc2b  = (const float*)d_in[23];
    const float* pcw   = (const float*)d_in[24];
    const float* pcb   = (const float*)d_in[25];
    float* out = (float*)d_out;

    float* p = (float*)d_ws;
    float* h      = p; p += 5120512;     // 10001 x 512
    float* yt     = p; p += 5120512;     // ppeg conv output (channel-major)
    float* ql     = p; p += 131072;
    float* kl     = p; p += 131072;
    float* x2     = p; p += 524288;
    float* scal   = p; p += 32;
    float* part   = p; p += 1081344;     // attn3 partials
    float* ft     = p; p += 5120512;     // ppeg channel-major input
    __hip_bfloat16* qh     = (__hip_bfloat16*)p; p += 2621440;   // [h][NPAD][64]
    __hip_bfloat16* kh     = (__hip_bfloat16*)p; p += 2621440;
    __hip_bfloat16* vh     = (__hip_bfloat16*)p; p += 2621440;
    __hip_bfloat16* xbf    = (__hip_bfloat16*)p; p += 2621440;   // 10240 x 512
    __hip_bfloat16* abf    = (__hip_bfloat16*)p; p += 2588672;   // 10112 x 512
    __hip_bfloat16* convbf = (__hip_bfloat16*)p; p += 2560256;   // 10001 x 512
    __hip_bfloat16* qw1t   = (__hip_bfloat16*)p; p += 393216;
    __hip_bfloat16* qw2t   = (__hip_bfloat16*)p; p += 393216;
    __hip_bfloat16* ow1t   = (__hip_bfloat16*)p; p += 131072;
    __hip_bfloat16* ow2t   = (__hip_bfloat16*)p; p += 131072;
    __hip_bfloat16* x2a    = (__hip_bfloat16*)p; p += 262144;
    __hip_bfloat16* za     = (__hip_bfloat16*)p; p += 262144;
    __hip_bfloat16* zt     = (__hip_bfloat16*)p; p += 262144;
    __hip_bfloat16* za2    = (__hip_bfloat16*)p; p += 262144;
    __hip_bfloat16* zt2    = (__hip_bfloat16*)p; p += 262144;
    __hip_bfloat16* xza    = (__hip_bfloat16*)p; p += 262144;
    __hip_bfloat16* xzt    = (__hip_bfloat16*)p; p += 262144;
    __hip_bfloat16* t1t    = (__hip_bfloat16*)p; p += 262144;
    __hip_bfloat16* t2t    = (__hip_bfloat16*)p; p += 262144;
    __hip_bfloat16* qlbf   = (__hip_bfloat16*)p; p += 65536;
    __hip_bfloat16* klbf   = (__hip_bfloat16*)p; p += 65536;
    __hip_bfloat16* vt     = (__hip_bfloat16*)p; p += 2621440;   // [h][64][NPAD]
    __hip_bfloat16* a3vt   = (__hip_bfloat16*)p; p += 65536;
    __hip_bfloat16* w2bt   = (__hip_bfloat16*)p; p += 65536;

    k_concat<<<dim3((NTOK * DIM + 255) / 256), 256, 0, stream>>>(x, cls, h);
    k_wt_cvt<<<dim3(16, 48), 256, 0, stream>>>(qkv1w, qw1t, 512, 1536);
    k_wt_cvt<<<dim3(16, 48), 256, 0, stream>>>(qkv2w, qw2t, 512, 1536);
    k_wt_cvt<<<dim3(16, 16), 256, 0, stream>>>(out1w, ow1t, 512, 512);
    k_wt_cvt<<<dim3(16, 16), 256, 0, stream>>>(out2w, ow2t, 512, 512);
    k_zerobf<<<dim3((PADR * DIM + 255) / 256), 256, 0, stream>>>(xbf, PADR * DIM);

    auto layer = [&](const float* lnw, const float* lnb, const __hip_bfloat16* qwt,
                     const __hip_bfloat16* owt, const float* outb, const float* resw) {
        k_layernorm_bf<<<NTOK, 256, 0, stream>>>(h, lnw, lnb, xbf);
        // qkv GEMM (global_load_lds staging) -> head-major qh/kh/vh (q pre-scaled 1/8)
        k_qkv_gemm<<<dim3(12, 80), 256, 0, stream>>>(xbf, qwt, qh, kh, vh);
        k_vt<<<dim3(320, 2, HEADS), 256, 0, stream>>>(vh, vt);
        k_landmarks<<<dim3(MLAND, HEADS), 64, 0, stream>>>(qh, kh, ql, kl, qlbf, klbf);
        k_attn2<<<dim3(MLAND, HEADS), 256, 0, stream>>>(ql, kl, x2, x2a);
        k_colrow<<<HEADS, 256, 0, stream>>>(x2, scal);
        k_tscale2<<<dim3(8, 8, HEADS), 256, 0, stream>>>(x2, scal, za, zt);
        // pinv: 24 launch-bound MFMA phases, 32x32 tiles -> 512 blocks (2 blocks/CU)
        {
            __hip_bfloat16 *zra = za, *zrt = zt, *zoa = za2, *zot = zt2;
            dim3 g(8, 8, HEADS);
            for (int it = 0; it < 6; it++) {
                k_mm256<<<g, 256, 0, stream>>>(x2a, zrt, 1.f, 0.f, nullptr, xza, xzt);
                k_mm256<<<g, 256, 0, stream>>>(xza, xzt, -1.f, 7.f, xza, nullptr, t1t);
                k_mm256<<<g, 256, 0, stream>>>(xza, t1t, -1.f, 15.f, xza, nullptr, t2t);
                k_mm256<<<g, 256, 0, stream>>>(zra, t2t, -0.25f, 3.25f, zra, zoa, zot);
                __hip_bfloat16* tmp;
                tmp = zra; zra = zoa; zoa = tmp;
                tmp = zrt; zrt = zot; zot = tmp;
            }
            // final z row-major bf16 ends in za
        }
        // attn3: flash split-N online softmax -> combine (writes a3vt directly)
        k_attn3f<<<dim3(NSPLIT, 4, HEADS), 256, 0, stream>>>(qlbf, kh, vt, part);
        k_a3comb<<<dim3(4, HEADS), 256, 0, stream>>>(part, a3vt);
        // w2b^T = (z @ a3v)^T bf16
        k_mfma_t64<<<dim3(1, 2, HEADS), 256, 0, stream>>>(
            za, 256, 65536, 256, a3vt, 256, 16384,
            w2bt, 256, 16384, 256);
        // conv residual (bf16, x4 vectorized) right before attn1f so convbf is L2-hot
        k_conv_res<<<dim3((NTOK * 128 + 255) / 256), 256, 0, stream>>>(vh, resw, convbf);
        // attn1: fused scores+softmax+P@w2 + convbf add -> abf (bf16)
        k_attn1f<<<dim3(157, HEADS), 256, 0, stream>>>(qh, klbf, w2bt, convbf, abf);
        // out-proj: global_load_lds GEMM, fp32 accumulate into h, +bias
        k_mfma_gemm<<<dim3(4, 79), 256, 0, stream>>>(abf, owt, h, MOUT, 512, 512,
                                                     NTOK, outb, 1);
    };

    layer(ln1w, ln1b, qw1t, ow1t, out1b, res1w);

    k_tfwd<<<dim3(313, 16), 256, 0, stream>>>(h, ft);
    k_ppeg2<<<dim3(5, 512), 256, 0, stream>>>(ft, yt, p7w, p7b, p5w, p5b, p3w, p3b);
    k_tback<<<dim3(313, 16), 256, 0, stream>>>(yt, h);

    layer(ln2w, ln2b, qw2t, ow2t, out2b, res2w);

    k_final<<<NTOK, 256, 0, stream>>>(h, normw, normb, fc2w, fc2b, pcw, pcb, out);
    (void)in_sizes; (void)n_in; (void)out_size; (void)ws_size;
}

// Round 19
// 1056.546 us; speedup vs baseline: 1.0166x; 1.0166x over previous
//
#include <hip/hip_runtime.h>
#include <hip/hip_bf16.h>

#define DIM    512
#define HEADS  8
#define DHD    64
#define MLAND  256
#define NTOK   10001
#define NPATCH 10000
#define NPAD   10240
#define PADR   239
#define LFAC   40
#define MOUT   10112
#define NSPLIT 8

typedef __bf16 bf16x8_t __attribute__((ext_vector_type(8)));
typedef float  f32x4_t  __attribute__((ext_vector_type(4)));
typedef short  short8_t __attribute__((ext_vector_type(8)));

__device__ inline bf16x8_t bzero8() {
    union { short8_t s; bf16x8_t b; } u;
    u.s = (short8_t){0, 0, 0, 0, 0, 0, 0, 0};
    return u.b;
}

#define GLDS(gp, lp) __builtin_amdgcn_global_load_lds( \
    (const __attribute__((address_space(1))) void*)(gp), \
    (__attribute__((address_space(3))) void*)(lp), 16, 0, 0)

// ---------------------------------------------------------------- concat
__global__ void k_concat(const float* __restrict__ x, const float* __restrict__ cls,
                         float* __restrict__ h) {
    int idx = blockIdx.x * 256 + threadIdx.x;
    if (idx >= NTOK * DIM) return;
    int row = idx / DIM, col = idx % DIM;
    h[idx] = (row == 0) ? cls[col] : x[(row - 1) * DIM + col];
}

// ---------------------------------------------------------------- layernorm -> bf16 padded A
__global__ void k_layernorm_bf(const float* __restrict__ h, const float* __restrict__ w,
                               const float* __restrict__ b, __hip_bfloat16* __restrict__ xbf) {
    int row = blockIdx.x;
    const float* r = h + (long)row * DIM;
    int t = threadIdx.x;
    float v0 = r[t], v1 = r[t + 256];
    __shared__ float red[256];
    red[t] = v0 + v1; __syncthreads();
    for (int o = 128; o > 0; o >>= 1) { if (t < o) red[t] += red[t + o]; __syncthreads(); }
    float mu = red[0] * (1.f / DIM); __syncthreads();
    float d0 = v0 - mu, d1 = v1 - mu;
    red[t] = d0 * d0 + d1 * d1; __syncthreads();
    for (int o = 128; o > 0; o >>= 1) { if (t < o) red[t] += red[t + o]; __syncthreads(); }
    float rstd = rsqrtf(red[0] * (1.f / DIM) + 1e-5f);
    long base = (long)(PADR + row) * DIM;
    xbf[base + t]       = __float2bfloat16(d0 * rstd * w[t] + b[t]);
    xbf[base + t + 256] = __float2bfloat16(d1 * rstd * w[t + 256] + b[t + 256]);
}

// ---------------------------------------------------------------- helpers
__global__ void k_zerobf(__hip_bfloat16* __restrict__ p, int n) {
    int i = blockIdx.x * 256 + threadIdx.x;
    if (i < n) p[i] = __float2bfloat16(0.f);
}
__global__ void k_wt_cvt(const float* __restrict__ W, __hip_bfloat16* __restrict__ Wt,
                         int K, int N) {
    __shared__ float tile[32][33];
    int k0 = blockIdx.x * 32, n0 = blockIdx.y * 32;
    int lx = threadIdx.x % 32, ly = threadIdx.x / 32;
    for (int i = 0; i < 32; i += 8) tile[ly + i][lx] = W[(long)(k0 + ly + i) * N + n0 + lx];
    __syncthreads();
    for (int i = 0; i < 32; i += 8)
        Wt[(long)(n0 + ly + i) * K + k0 + lx] = __float2bfloat16(tile[lx][ly + i]);
}
// vh [h][n][d] -> vt [h][d][n]
__global__ void k_vt(const __hip_bfloat16* __restrict__ vh, __hip_bfloat16* __restrict__ vt) {
    __shared__ __hip_bfloat16 tile[32][33];
    int n0 = blockIdx.x * 32, d0 = blockIdx.y * 32, h = blockIdx.z;
    int lx = threadIdx.x % 32, ly = threadIdx.x / 32;
    for (int i = 0; i < 32; i += 8)
        tile[ly + i][lx] = vh[((long)h * NPAD + n0 + ly + i) * 64 + d0 + lx];
    __syncthreads();
    for (int i = 0; i < 32; i += 8)
        vt[((long)h * 64 + d0 + ly + i) * NPAD + n0 + lx] = tile[lx][ly + i];
}

// ---------------------------------------------------------------- qkv GEMM 128x128 BK=64, global_load_lds staging
__global__ __launch_bounds__(256) void k_qkv_gemm(
    const __hip_bfloat16* __restrict__ A, const __hip_bfloat16* __restrict__ Bt,
    __hip_bfloat16* __restrict__ qh, __hip_bfloat16* __restrict__ kh,
    __hip_bfloat16* __restrict__ vh)
{
    const int K = 512;
    __shared__ unsigned short As[128 * 64];
    __shared__ unsigned short Bs[128 * 64];
    int tid = threadIdx.x;
    int m0 = blockIdx.y * 128, n0 = blockIdx.x * 128;
    int wave = tid >> 6, lane = tid & 63;
    int wm = (wave & 1) * 64, wn = (wave >> 1) * 64;
    f32x4_t zero4 = {0.f, 0.f, 0.f, 0.f};
    f32x4_t acc[4][4];
#pragma unroll
    for (int i = 0; i < 4; i++)
#pragma unroll
        for (int j = 0; j < 4; j++) acc[i][j] = zero4;
    int quad = lane >> 4, fr = lane & 15;
    int lrow8 = lane >> 3, gls = lane & 7;
    int gg = gls ^ lrow8;

    for (int k0 = 0; k0 < K; k0 += 64) {
        __syncthreads();
#pragma unroll
        for (int rnd = 0; rnd < 4; rnd++) {
            int r0 = rnd * 32 + wave * 8;
            int ar = r0 + lrow8;
            GLDS(A  + (long)(m0 + ar) * K + k0 + gg * 8, &As[r0 * 64]);
            GLDS(Bt + (long)(n0 + ar) * K + k0 + gg * 8, &Bs[r0 * 64]);
        }
        __syncthreads();
#pragma unroll
        for (int ks = 0; ks < 2; ks++) {
            int sg = (ks * 4 + quad) ^ (fr & 7);
            bf16x8_t af[4], bq[4];
#pragma unroll
            for (int i = 0; i < 4; i++) {
                af[i] = *(const bf16x8_t*)&As[(wm + i * 16 + fr) * 64 + sg * 8];
                bq[i] = *(const bf16x8_t*)&Bs[(wn + i * 16 + fr) * 64 + sg * 8];
            }
#pragma unroll
            for (int i = 0; i < 4; i++)
#pragma unroll
                for (int j = 0; j < 4; j++)
                    acc[i][j] = __builtin_amdgcn_mfma_f32_16x16x32_bf16(af[i], bq[j], acc[i][j], 0, 0, 0);
        }
    }
    int col = lane & 15, rq = lane >> 4;
#pragma unroll
    for (int j = 0; j < 4; j++) {
        int c = n0 + wn + j * 16 + col;
        int sect = c >> 9;          // 0=q 1=k 2=v
        int hh = (c >> 6) & 7;
        int d = c & 63;
        __hip_bfloat16* dst = (sect == 0) ? qh : (sect == 1) ? kh : vh;
        float sc = (sect == 0) ? 0.125f : 1.f;
#pragma unroll
        for (int i = 0; i < 4; i++) {
            int rbase = m0 + wm + i * 16 + rq * 4;
#pragma unroll
            for (int rr = 0; rr < 4; rr++) {
                int r = rbase + rr;
                dst[((long)hh * NPAD + r) * 64 + d] = __float2bfloat16(acc[i][j][rr] * sc);
            }
        }
    }
}

// ---------------------------------------------------------------- out-proj GEMM 128x128 BK=64, global_load_lds staging
__global__ __launch_bounds__(256) void k_mfma_gemm(
    const __hip_bfloat16* __restrict__ A, const __hip_bfloat16* __restrict__ Bt,
    float* __restrict__ C, int M, int N, int K, int Mstore,
    const float* __restrict__ bias, int accum)
{
    __shared__ unsigned short As[128 * 64];
    __shared__ unsigned short Bs[128 * 64];
    int tid = threadIdx.x;
    int m0 = blockIdx.y * 128, n0 = blockIdx.x * 128;
    int wave = tid >> 6, lane = tid & 63;
    int wm = (wave & 1) * 64, wn = (wave >> 1) * 64;
    f32x4_t zero4 = {0.f, 0.f, 0.f, 0.f};
    f32x4_t acc[4][4];
#pragma unroll
    for (int i = 0; i < 4; i++)
#pragma unroll
        for (int j = 0; j < 4; j++) acc[i][j] = zero4;
    int quad = lane >> 4, fr = lane & 15;
    int lrow8 = lane >> 3, gls = lane & 7;
    int gg = gls ^ lrow8;

    for (int k0 = 0; k0 < K; k0 += 64) {
        __syncthreads();
#pragma unroll
        for (int rnd = 0; rnd < 4; rnd++) {
            int r0 = rnd * 32 + wave * 8;
            int ar = r0 + lrow8;
            GLDS(A  + (long)(m0 + ar) * K + k0 + gg * 8, &As[r0 * 64]);
            GLDS(Bt + (long)(n0 + ar) * K + k0 + gg * 8, &Bs[r0 * 64]);
        }
        __syncthreads();
#pragma unroll
        for (int ks = 0; ks < 2; ks++) {
            int sg = (ks * 4 + quad) ^ (fr & 7);
            bf16x8_t af[4], bq[4];
#pragma unroll
            for (int i = 0; i < 4; i++) {
                af[i] = *(const bf16x8_t*)&As[(wm + i * 16 + fr) * 64 + sg * 8];
                bq[i] = *(const bf16x8_t*)&Bs[(wn + i * 16 + fr) * 64 + sg * 8];
            }
#pragma unroll
            for (int i = 0; i < 4; i++)
#pragma unroll
                for (int j = 0; j < 4; j++)
                    acc[i][j] = __builtin_amdgcn_mfma_f32_16x16x32_bf16(af[i], bq[j], acc[i][j], 0, 0, 0);
        }
    }
    int col = lane & 15, rq = lane >> 4;
#pragma unroll
    for (int j = 0; j < 4; j++) {
        int c = n0 + wn + j * 16 + col;
        float bsv = bias ? bias[c] : 0.f;
#pragma unroll
        for (int i = 0; i < 4; i++) {
            int rbase = m0 + wm + i * 16 + rq * 4;
#pragma unroll
            for (int rr = 0; rr < 4; rr++) {
                int r = rbase + rr;
                if (r >= Mstore) continue;
                float v = acc[i][j][rr] + bsv;
                long off = (long)r * N + c;
                if (accum) C[off] += v; else C[off] = v;
            }
        }
    }
}

// ---------------------------------------------------------------- generic MFMA 128x64, bf16-T out (w2bt)
__global__ __launch_bounds__(256) void k_mfma_t64(
    const __hip_bfloat16* __restrict__ A, long lda, long abatch, int arowmax,
    const __hip_bfloat16* __restrict__ Bt, long ldb, long bbatch,
    __hip_bfloat16* __restrict__ Cbf, long ldc, long cbatch, int ksplit)
{
    int h = blockIdx.z;
    const __hip_bfloat16* Ab = A + (long)h * abatch;
    const __hip_bfloat16* Bb = Bt + (long)h * bbatch;
    int m0 = blockIdx.y * 128;
    int kbeg = blockIdx.x * ksplit, kend = kbeg + ksplit;
    int wave = threadIdx.x >> 6, lane = threadIdx.x & 63;
    int wm = (wave & 1) * 64, wn = (wave >> 1) * 32;
    int fr = lane & 15, quad = lane >> 4;
    f32x4_t zero4 = {0.f, 0.f, 0.f, 0.f};
    f32x4_t acc[4][2];
#pragma unroll
    for (int i = 0; i < 4; i++) { acc[i][0] = zero4; acc[i][1] = zero4; }
    for (int k0 = kbeg; k0 < kend; k0 += 32) {
        bf16x8_t bq[2];
#pragma unroll
        for (int j = 0; j < 2; j++)
            bq[j] = *(const bf16x8_t*)(Bb + (long)(wn + j * 16 + fr) * ldb + k0 + quad * 8);
#pragma unroll
        for (int i = 0; i < 4; i++) {
            int r = m0 + wm + i * 16 + fr;
            bf16x8_t af = (r < arowmax) ? *(const bf16x8_t*)(Ab + (long)r * lda + k0 + quad * 8)
                                        : bzero8();
#pragma unroll
            for (int j = 0; j < 2; j++)
                acc[i][j] = __builtin_amdgcn_mfma_f32_16x16x32_bf16(af, bq[j], acc[i][j], 0, 0, 0);
        }
    }
#pragma unroll
    for (int i = 0; i < 4; i++)
#pragma unroll
        for (int j = 0; j < 2; j++)
#pragma unroll
            for (int rr = 0; rr < 4; rr++) {
                int r = m0 + wm + i * 16 + quad * 4 + rr;
                int c = wn + j * 16 + fr;
                Cbf[(long)h * cbatch + (long)c * ldc + r] = __float2bfloat16(acc[i][j][rr]);
            }
}

// ---------------------------------------------------------------- pinv phase: C = s*(A@B) + acoef*Aadd, per head
// 64x32 tile, grid (8,4,HEADS) = 256 blocks -> full CU coverage (round-17 measured best)
__global__ __launch_bounds__(256) void k_mm256(
    const __hip_bfloat16* __restrict__ Aa, const __hip_bfloat16* __restrict__ Bt,
    float s, float acoef, const __hip_bfloat16* __restrict__ Aadd,
    __hip_bfloat16* __restrict__ Ca, __hip_bfloat16* __restrict__ Ct)
{
    int hd = blockIdx.z;
    long hb = (long)hd * 65536;
    int m0 = blockIdx.y * 64, n0 = blockIdx.x * 32;
    int wave = threadIdx.x >> 6, lane = threadIdx.x & 63;
    int fr = lane & 15, quad = lane >> 4;
    int mrow = m0 + wave * 16;
    f32x4_t zero4 = {0.f, 0.f, 0.f, 0.f};
    f32x4_t acc[2];
    acc[0] = zero4; acc[1] = zero4;
#pragma unroll
    for (int k0 = 0; k0 < 256; k0 += 32) {
        bf16x8_t af = *(const bf16x8_t*)(Aa + hb + (long)(mrow + fr) * 256 + k0 + quad * 8);
#pragma unroll
        for (int j = 0; j < 2; j++) {
            bf16x8_t bq = *(const bf16x8_t*)(Bt + hb + (long)(n0 + j * 16 + fr) * 256 + k0 + quad * 8);
            acc[j] = __builtin_amdgcn_mfma_f32_16x16x32_bf16(af, bq, acc[j], 0, 0, 0);
        }
    }
#pragma unroll
    for (int j = 0; j < 2; j++)
#pragma unroll
        for (int rr = 0; rr < 4; rr++) {
            int r = mrow + quad * 4 + rr;
            int c = n0 + j * 16 + fr;
            float v = s * acc[j][rr];
            if (Aadd) v += acoef * __bfloat162float(Aadd[hb + (long)r * 256 + c]);
            __hip_bfloat16 bv = __float2bfloat16(v);
            if (Ca) Ca[hb + (long)r * 256 + c] = bv;
            if (Ct) Ct[hb + (long)c * 256 + r] = bv;
        }
}

// ---------------------------------------------------------------- flash attn3: split-N online softmax, partial O/m/l
__global__ __launch_bounds__(256) void k_attn3f(
    const __hip_bfloat16* __restrict__ qlbf, const __hip_bfloat16* __restrict__ kh,
    const __hip_bfloat16* __restrict__ vt, float* __restrict__ part)
{
    int ns = blockIdx.x, mt = blockIdx.y, h = blockIdx.z;
    int wave = threadIdx.x >> 6, lane = threadIdx.x & 63;
    int fr = lane & 15, quad = lane >> 4;
    __shared__ __hip_bfloat16 Pl[64 * 264];
    f32x4_t zero4 = {0.f, 0.f, 0.f, 0.f};
    bf16x8_t aq[2];
    {
        const __hip_bfloat16* qb = qlbf + (long)h * 16384 + (long)(mt * 64 + wave * 16 + fr) * 64;
        aq[0] = *(const bf16x8_t*)(qb + quad * 8);
        aq[1] = *(const bf16x8_t*)(qb + 32 + quad * 8);
    }
    f32x4_t O[4];
#pragma unroll
    for (int j = 0; j < 4; j++) O[j] = zero4;
    float mr[4] = {-1e30f, -1e30f, -1e30f, -1e30f};
    float lr[4] = {0.f, 0.f, 0.f, 0.f};
    const __hip_bfloat16* kb = kh + (long)h * NPAD * 64;
    const __hip_bfloat16* vb = vt + (long)h * 64 * NPAD;

    for (int nt = 0; nt < 5; nt++) {
        int n0 = ns * 1280 + nt * 256;
        f32x4_t s[16];
#pragma unroll
        for (int j = 0; j < 16; j++) s[j] = zero4;
#pragma unroll
        for (int j = 0; j < 16; j++) {
            const __hip_bfloat16* kr = kb + (long)(n0 + j * 16 + fr) * 64;
            bf16x8_t b0 = *(const bf16x8_t*)(kr + quad * 8);
            bf16x8_t b1 = *(const bf16x8_t*)(kr + 32 + quad * 8);
            s[j] = __builtin_amdgcn_mfma_f32_16x16x32_bf16(aq[0], b0, s[j], 0, 0, 0);
            s[j] = __builtin_amdgcn_mfma_f32_16x16x32_bf16(aq[1], b1, s[j], 0, 0, 0);
        }
        float tm[4] = {-1e30f, -1e30f, -1e30f, -1e30f};
#pragma unroll
        for (int j = 0; j < 16; j++)
#pragma unroll
            for (int rr = 0; rr < 4; rr++) tm[rr] = fmaxf(tm[rr], s[j][rr]);
#pragma unroll
        for (int rr = 0; rr < 4; rr++) {
#pragma unroll
            for (int o = 8; o > 0; o >>= 1) tm[rr] = fmaxf(tm[rr], __shfl_xor(tm[rr], o));
        }
        float alpha[4], ts[4];
#pragma unroll
        for (int rr = 0; rr < 4; rr++) {
            float mnew = fmaxf(mr[rr], tm[rr]);
            alpha[rr] = __expf(mr[rr] - mnew);
            mr[rr] = mnew;
            ts[rr] = 0.f;
        }
#pragma unroll
        for (int j = 0; j < 16; j++)
#pragma unroll
            for (int rr = 0; rr < 4; rr++) {
                float e = __expf(s[j][rr] - mr[rr]);
                s[j][rr] = e;
                ts[rr] += e;
            }
#pragma unroll
        for (int rr = 0; rr < 4; rr++) {
#pragma unroll
            for (int o = 8; o > 0; o >>= 1) ts[rr] += __shfl_xor(ts[rr], o);
            lr[rr] = lr[rr] * alpha[rr] + ts[rr];
        }
#pragma unroll
        for (int j = 0; j < 4; j++)
#pragma unroll
            for (int rr = 0; rr < 4; rr++) O[j][rr] *= alpha[rr];
        __syncthreads();
#pragma unroll
        for (int j = 0; j < 16; j++)
#pragma unroll
            for (int rr = 0; rr < 4; rr++)
                Pl[(wave * 16 + quad * 4 + rr) * 264 + j * 16 + fr] = __float2bfloat16(s[j][rr]);
        __syncthreads();
#pragma unroll
        for (int k0 = 0; k0 < 256; k0 += 32) {
            bf16x8_t af = *(const bf16x8_t*)&Pl[(wave * 16 + fr) * 264 + k0 + quad * 8];
#pragma unroll
            for (int j = 0; j < 4; j++) {
                bf16x8_t bq = *(const bf16x8_t*)(vb + (long)(j * 16 + fr) * NPAD + n0 + k0 + quad * 8);
                O[j] = __builtin_amdgcn_mfma_f32_16x16x32_bf16(af, bq, O[j], 0, 0, 0);
            }
        }
    }
    float* Ob = part + (long)((h * 4 + mt) * NSPLIT + ns) * 4224;
#pragma unroll
    for (int j = 0; j < 4; j++)
#pragma unroll
        for (int rr = 0; rr < 4; rr++)
            Ob[(wave * 16 + quad * 4 + rr) * 64 + j * 16 + fr] = O[j][rr];
    if (fr == 0) {
#pragma unroll
        for (int rr = 0; rr < 4; rr++) {
            Ob[4096 + wave * 16 + quad * 4 + rr] = mr[rr];
            Ob[4160 + wave * 16 + quad * 4 + rr] = lr[rr];
        }
    }
}

// ---------------------------------------------------------------- combine attn3 partials -> a3vt bf16 [h][64][256]
__global__ void k_a3comb(const float* __restrict__ part, __hip_bfloat16* __restrict__ a3vt) {
    int mt = blockIdx.x, h = blockIdx.y, t = threadIdx.x;
    int row = t >> 2, c0 = (t & 3) * 16;
    long base = (long)((h * 4 + mt) * NSPLIT) * 4224;
    float M = -1e30f;
    for (int s = 0; s < NSPLIT; s++) M = fmaxf(M, part[base + s * 4224 + 4096 + row]);
    float L = 0.f;
    float o[16];
#pragma unroll
    for (int c = 0; c < 16; c++) o[c] = 0.f;
    for (int s = 0; s < NSPLIT; s++) {
        const float* pb = part + base + (long)s * 4224;
        float w = __expf(pb[4096 + row] - M);
        L += pb[4160 + row] * w;
#pragma unroll
        for (int c = 0; c < 16; c++) o[c] += w * pb[row * 64 + c0 + c];
    }
    float invL = 1.f / L;
#pragma unroll
    for (int c = 0; c < 16; c++)
        a3vt[(long)h * 16384 + (long)(c0 + c) * 256 + mt * 64 + row] = __float2bfloat16(o[c] * invL);
}

// ---------------------------------------------------------------- conv residual -> convbf (bf16), x4 vectorized
__global__ void k_conv_res(const __hip_bfloat16* __restrict__ vh, const float* __restrict__ resw,
                           __hip_bfloat16* __restrict__ convbf) {
    int e4 = blockIdx.x * 256 + threadIdx.x;
    if (e4 >= NTOK * 128) return;
    int i = e4 >> 7;
    int c4 = (e4 & 127) * 4;
    int hh = c4 >> 6, d = c4 & 63;
    int n = PADR + i;
    const __hip_bfloat16* vb = vh + (long)hh * NPAD * 64 + d;
    float a0 = 0.f, a1 = 0.f, a2 = 0.f, a3 = 0.f;
#pragma unroll
    for (int t = 0; t < 33; t++) {
        int nn = n - 16 + t;
        if (nn < NPAD) {
            float w = resw[hh * 33 + t];
            uint2 pv = *(const uint2*)(vb + (long)nn * 64);
            __hip_bfloat16 vv[4];
            *(uint2*)vv = pv;
            a0 += w * __bfloat162float(vv[0]);
            a1 += w * __bfloat162float(vv[1]);
            a2 += w * __bfloat162float(vv[2]);
            a3 += w * __bfloat162float(vv[3]);
        }
    }
    __hip_bfloat16 o[4] = {__float2bfloat16(a0), __float2bfloat16(a1),
                           __float2bfloat16(a2), __float2bfloat16(a3)};
    *(uint2*)(convbf + (long)i * DIM + c4) = *(uint2*)o;
}

// ---------------------------------------------------------------- fused attn1: scores -> softmax -> P@w2 -> +convbf -> abf
__global__ __launch_bounds__(256) void k_attn1f(
    const __hip_bfloat16* __restrict__ qh, const __hip_bfloat16* __restrict__ klbf,
    const __hip_bfloat16* __restrict__ w2bt, const __hip_bfloat16* __restrict__ convbf,
    __hip_bfloat16* __restrict__ abf)
{
    int h = blockIdx.y;
    int i0 = blockIdx.x * 64;
    __shared__ __hip_bfloat16 Pl[64 * 264];
    int tid = threadIdx.x;
    int wave = tid >> 6, lane = tid & 63;
    int fr = lane & 15, quad = lane >> 4;
    const __hip_bfloat16* kb = klbf + (long)h * (MLAND * DHD);
    f32x4_t zero4 = {0.f, 0.f, 0.f, 0.f};
    float cpre[4][4];
#pragma unroll
    for (int j = 0; j < 4; j++)
#pragma unroll
        for (int rr = 0; rr < 4; rr++) {
            int r = i0 + wave * 16 + quad * 4 + rr;
            cpre[j][rr] = (r < NTOK)
                ? __bfloat162float(convbf[(long)r * DIM + h * DHD + j * 16 + fr]) : 0.f;
        }
    f32x4_t acc[16];
#pragma unroll
    for (int j = 0; j < 16; j++) acc[j] = zero4;
    int arow = i0 + wave * 16 + fr;
    const __hip_bfloat16* qrow = qh + ((long)h * NPAD + PADR + arow) * 64;
#pragma unroll
    for (int k0 = 0; k0 < 64; k0 += 32) {
        bf16x8_t af = (arow < NTOK) ? *(const bf16x8_t*)(qrow + k0 + quad * 8) : bzero8();
#pragma unroll
        for (int j = 0; j < 16; j++) {
            bf16x8_t bq = *(const bf16x8_t*)(kb + (long)(j * 16 + fr) * DHD + k0 + quad * 8);
            acc[j] = __builtin_amdgcn_mfma_f32_16x16x32_bf16(af, bq, acc[j], 0, 0, 0);
        }
    }
    float mx[4] = {-1e30f, -1e30f, -1e30f, -1e30f};
#pragma unroll
    for (int j = 0; j < 16; j++)
#pragma unroll
        for (int rr = 0; rr < 4; rr++) mx[rr] = fmaxf(mx[rr], acc[j][rr]);
#pragma unroll
    for (int rr = 0; rr < 4; rr++) {
#pragma unroll
        for (int o = 8; o > 0; o >>= 1) mx[rr] = fmaxf(mx[rr], __shfl_xor(mx[rr], o));
    }
    float sum[4] = {0.f, 0.f, 0.f, 0.f};
#pragma unroll
    for (int j = 0; j < 16; j++)
#pragma unroll
        for (int rr = 0; rr < 4; rr++) {
            float e = __expf(acc[j][rr] - mx[rr]);
            acc[j][rr] = e;
            sum[rr] += e;
        }
#pragma unroll
    for (int rr = 0; rr < 4; rr++) {
#pragma unroll
        for (int o = 8; o > 0; o >>= 1) sum[rr] += __shfl_xor(sum[rr], o);
    }
#pragma unroll
    for (int j = 0; j < 16; j++)
#pragma unroll
        for (int rr = 0; rr < 4; rr++)
            Pl[(wave * 16 + quad * 4 + rr) * 264 + j * 16 + fr] =
                __float2bfloat16(acc[j][rr] / sum[rr]);
    __syncthreads();
    const __hip_bfloat16* wb = w2bt + (long)h * (DHD * MLAND);
    f32x4_t oc[4];
#pragma unroll
    for (int j = 0; j < 4; j++) oc[j] = zero4;
#pragma unroll
    for (int k0 = 0; k0 < 256; k0 += 32) {
        bf16x8_t af = *(const bf16x8_t*)&Pl[(wave * 16 + fr) * 264 + k0 + quad * 8];
#pragma unroll
        for (int j = 0; j < 4; j++) {
            bf16x8_t bq = *(const bf16x8_t*)(wb + (long)(j * 16 + fr) * MLAND + k0 + quad * 8);
            oc[j] = __builtin_amdgcn_mfma_f32_16x16x32_bf16(af, bq, oc[j], 0, 0, 0);
        }
    }
#pragma unroll
    for (int j = 0; j < 4; j++)
#pragma unroll
        for (int rr = 0; rr < 4; rr++) {
            int r = i0 + wave * 16 + quad * 4 + rr;
            if (r < NTOK) {
                long off = (long)r * DIM + h * DHD + j * 16 + fr;
                abf[off] = __float2bfloat16(cpre[j][rr] + oc[j][rr]);
            }
        }
}

// ---------------------------------------------------------------- landmark means (head-major in; fp32 + bf16 out)
__global__ void k_landmarks(const __hip_bfloat16* __restrict__ qh,
                            const __hip_bfloat16* __restrict__ kh,
                            float* __restrict__ ql, float* __restrict__ kl,
                            __hip_bfloat16* __restrict__ qlbf, __hip_bfloat16* __restrict__ klbf) {
    int m = blockIdx.x, h = blockIdx.y, d = threadIdx.x;
    float sq = 0.f, sk = 0.f;
    for (int j = 0; j < LFAC; j++) {
        long base = ((long)h * NPAD + m * LFAC + j) * 64 + d;
        sq += __bfloat162float(qh[base]);
        sk += __bfloat162float(kh[base]);
    }
    long o = ((long)h * MLAND + m) * DHD + d;
    float vq = sq * (1.f / LFAC), vk = sk * (1.f / LFAC);
    ql[o] = vq; kl[o] = vk;
    qlbf[o] = __float2bfloat16(vq);
    klbf[o] = __float2bfloat16(vk);
}

// ---------------------------------------------------------------- attn2 = softmax(q_l @ k_l^T), fp32 + bf16 out
__global__ void k_attn2(const float* __restrict__ ql, const float* __restrict__ kl,
                        float* __restrict__ attn2, __hip_bfloat16* __restrict__ attn2bf) {
    int i = blockIdx.x, h = blockIdx.y, j = threadIdx.x;
    __shared__ float q[64];
    __shared__ float red[256];
    if (j < 64) q[j] = ql[((long)h * MLAND + i) * DHD + j];
    __syncthreads();
    const float* kr = kl + ((long)h * MLAND + j) * DHD;
    float s = 0.f;
#pragma unroll 8
    for (int d = 0; d < 64; d++) s += q[d] * kr[d];
    red[j] = s; __syncthreads();
    for (int o = 128; o > 0; o >>= 1) { if (j < o) red[j] = fmaxf(red[j], red[j + o]); __syncthreads(); }
    float mx = red[0]; __syncthreads();
    float e = __expf(s - mx);
    red[j] = e; __syncthreads();
    for (int o = 128; o > 0; o >>= 1) { if (j < o) red[j] += red[j + o]; __syncthreads(); }
    float v = e / red[0];
    long off = ((long)h * MLAND + i) * MLAND + j;
    attn2[off] = v;
    attn2bf[off] = __float2bfloat16(v);
}

// ---------------------------------------------------------------- pinv scale: per-head col/row max sums (no atomics)
__global__ void k_colrow(const float* __restrict__ x, float* __restrict__ scal) {
    int h = blockIdx.x, t = threadIdx.x;
    const float* xh = x + (long)h * MLAND * MLAND;
    float cs = 0.f, rs = 0.f;
    for (int j = 0; j < MLAND; j++) {
        cs += fabsf(xh[(long)t * MLAND + j]);
        rs += fabsf(xh[(long)j * MLAND + t]);
    }
    __shared__ float red[256];
    red[t] = cs; __syncthreads();
    for (int o = 128; o > 0; o >>= 1) { if (t < o) red[t] = fmaxf(red[t], red[t + o]); __syncthreads(); }
    if (t == 0) scal[2 + h] = red[0];
    __syncthreads();
    red[t] = rs; __syncthreads();
    for (int o = 128; o > 0; o >>= 1) { if (t < o) red[t] = fmaxf(red[t], red[t + o]); __syncthreads(); }
    if (t == 0) scal[10 + h] = red[0];
}

// ---------------------------------------------------------------- z0 init (za = x^T*inv, zt = x*inv); global max inline
__global__ void k_tscale2(const float* __restrict__ x, const float* __restrict__ scal,
                          __hip_bfloat16* __restrict__ za, __hip_bfloat16* __restrict__ zt) {
    int h = blockIdx.z;
    int tj = blockIdx.x * 32, ti = blockIdx.y * 32;
    __shared__ float tile[32][33];
    const float* xh = x + (long)h * 65536;
    int lx = threadIdx.x % 32, ly = threadIdx.x / 32;
    float cm = scal[2], rm = scal[10];
#pragma unroll
    for (int k = 1; k < 8; k++) {
        cm = fmaxf(cm, scal[2 + k]);
        rm = fmaxf(rm, scal[10 + k]);
    }
    float inv = 1.f / (cm * rm);
    for (int yy = 0; yy < 32; yy += 8) {
        float v = xh[(long)(ti + ly + yy) * MLAND + tj + lx];
        tile[ly + yy][lx] = v;
        zt[(long)h * 65536 + (long)(ti + ly + yy) * MLAND + tj + lx] = __float2bfloat16(v * inv);
    }
    __syncthreads();
    for (int yy = 0; yy < 32; yy += 8)
        za[(long)h * 65536 + (long)(tj + ly + yy) * MLAND + ti + lx] =
            __float2bfloat16(tile[lx][ly + yy] * inv);
}

// ---------------------------------------------------------------- ppeg transposes + combined 49-tap conv
__global__ void k_tfwd(const float* __restrict__ h, float* __restrict__ ft) {
    __shared__ float tile[32][33];
    int t0 = blockIdx.x * 32, c0 = blockIdx.y * 32;
    int lx = threadIdx.x % 32, ly = threadIdx.x / 32;
    for (int i = 0; i < 32; i += 8) {
        int t = t0 + ly + i;
        if (t < NPATCH) tile[ly + i][lx] = h[(long)(1 + t) * DIM + c0 + lx];
    }
    __syncthreads();
    for (int i = 0; i < 32; i += 8) {
        int c = c0 + ly + i, t = t0 + lx;
        if (t < NPATCH) ft[(long)c * NPATCH + t] = tile[lx][ly + i];
    }
}

__global__ __launch_bounds__(256) void k_ppeg2(
    const float* __restrict__ ft, float* __restrict__ yt,
    const float* __restrict__ w7, const float* __restrict__ b7,
    const float* __restrict__ w5, const float* __restrict__ b5,
    const float* __restrict__ w3, const float* __restrict__ b3)
{
    int s = blockIdx.x, c = blockIdx.y;
    __shared__ float tile[26][106];
    __shared__ float wt[49];
    int tid = threadIdx.x;
    int r0 = s * 20 - 3;
    for (int idx = tid; idx < 26 * 106; idx += 256) {
        int rr = idx / 106, cc = idx % 106;
        int gy = r0 + rr, gx = cc - 3;
        float v = 0.f;
        if (gy >= 0 && gy < 100 && gx >= 0 && gx < 100)
            v = ft[(long)c * NPATCH + gy * 100 + gx];
        tile[rr][cc] = v;
    }
    if (tid < 49) {
        int dy = tid / 7 - 3, dx = tid % 7 - 3;
        float w = w7[c * 49 + tid];
        if (dy >= -2 && dy <= 2 && dx >= -2 && dx <= 2) w += w5[c * 25 + (dy + 2) * 5 + (dx + 2)];
        if (dy >= -1 && dy <= 1 && dx >= -1 && dx <= 1) w += w3[c * 9 + (dy + 1) * 3 + (dx + 1)];
        wt[tid] = w;
    }
    __syncthreads();
    float bsum = b7[c] + b5[c] + b3[c];
    for (int p = tid; p < 2000; p += 256) {
        int ly = p / 100, lx = p % 100;
        float acc = tile[ly + 3][lx + 3] + bsum;
#pragma unroll
        for (int dy = 0; dy < 7; dy++)
#pragma unroll
            for (int dx = 0; dx < 7; dx++)
                acc += wt[dy * 7 + dx] * tile[ly + dy][lx + dx];
        yt[(long)c * NPATCH + (s * 20 + ly) * 100 + lx] = acc;
    }
}

__global__ void k_tback(const float* __restrict__ yt, float* __restrict__ h) {
    __shared__ float tile[32][33];
    int t0 = blockIdx.x * 32, c0 = blockIdx.y * 32;
    int lx = threadIdx.x % 32, ly = threadIdx.x / 32;
    for (int i = 0; i < 32; i += 8) {
        int c = c0 + ly + i, t = t0 + lx;
        if (t < NPATCH) tile[ly + i][lx] = yt[(long)c * NPATCH + t];
    }
    __syncthreads();
    for (int i = 0; i < 32; i += 8) {
        int t = t0 + ly + i;
        if (t < NPATCH) h[(long)(1 + t) * DIM + c0 + lx] = tile[lx][ly + i];
    }
}

// ---------------------------------------------------------------- final LN + heads + softmax
__global__ void k_final(const float* __restrict__ h, const float* __restrict__ nw,
                        const float* __restrict__ nb,
                        const float* __restrict__ fc2w, const float* __restrict__ fc2b,
                        const float* __restrict__ pcw, const float* __restrict__ pcb,
                        float* __restrict__ out)
{
    int row = blockIdx.x;
    int t = threadIdx.x;
    const float* r = h + (long)row * DIM;
    float v0 = r[t], v1 = r[t + 256];
    __shared__ float red[256];
    red[t] = v0 + v1; __syncthreads();
    for (int o = 128; o > 0; o >>= 1) { if (t < o) red[t] += red[t + o]; __syncthreads(); }
    float mu = red[0] * (1.f / DIM); __syncthreads();
    float d0 = v0 - mu, d1 = v1 - mu;
    red[t] = d0 * d0 + d1 * d1; __syncthreads();
    for (int o = 128; o > 0; o >>= 1) { if (t < o) red[t] += red[t + o]; __syncthreads(); }
    float rstd = rsqrtf(red[0] * (1.f / DIM) + 1e-5f); __syncthreads();
    float h0 = d0 * rstd * nw[t] + nb[t];
    float h1 = d1 * rstd * nw[t + 256] + nb[t + 256];
    const float* w = (row == 0) ? fc2w : pcw;
    float p0 = h0 * w[t * 2] + h1 * w[(t + 256) * 2];
    float p1 = h0 * w[t * 2 + 1] + h1 * w[(t + 256) * 2 + 1];
    red[t] = p0; __syncthreads();
    for (int o = 128; o > 0; o >>= 1) { if (t < o) red[t] += red[t + o]; __syncthreads(); }
    float l0 = red[0]; __syncthreads();
    red[t] = p1; __syncthreads();
    for (int o = 128; o > 0; o >>= 1) { if (t < o) red[t] += red[t + o]; __syncthreads(); }
    if (t == 0) {
        float l1 = red[0];
        const float* bb = (row == 0) ? fc2b : pcb;
        float a0 = l0 + bb[0], a1 = l1 + bb[1];
        if (row == 0) { out[0] = a0; out[1] = a1; }
        else {
            long i = row - 1;
            out[2 + i * 2] = a0;
            out[2 + i * 2 + 1] = a1;
            float m = fmaxf(a0, a1);
            float e0 = __expf(a0 - m), e1 = __expf(a1 - m);
            float inv = 1.f / (e0 + e1);
            out[2 + 2 * NPATCH + i * 2] = e0 * inv;
            out[2 + 2 * NPATCH + i * 2 + 1] = e1 * inv;
        }
    }
}

// ================================================================ launcher
extern "C" void kernel_launch(void* const* d_in, const int* in_sizes, int n_in,
                              void* d_out, int out_size, void* d_ws, size_t ws_size,
                              hipStream_t stream)
{
    const float* x     = (const float*)d_in[0];
    const float* cls   = (const float*)d_in[1];
    const float* ln1w  = (const float*)d_in[2];
    const float* ln1b  = (const float*)d_in[3];
    const float* qkv1w = (const float*)d_in[4];
    const float* out1w = (const float*)d_in[5];
    const float* out1b = (const float*)d_in[6];
    const float* res1w = (const float*)d_in[7];
    const float* p7w   = (const float*)d_in[8];
    const float* p7b   = (const float*)d_in[9];
    const float* p5w   = (const float*)d_in[10];
    const float* p5b   = (const float*)d_in[11];
    const float* p3w   = (const float*)d_in[12];
    const float* p3b   = (const float*)d_in[13];
    const float* ln2w  = (const float*)d_in[14];
    const float* ln2b  = (const float*)d_in[15];
    const float* qkv2w = (const float*)d_in[16];
    const float* out2w = (const float*)d_in[17];
    const float* out2b = (const float*)d_in[18];
    const float* res2w = (const float*)d_in[19];
    const float* normw = (const float*)d_in[20];
    const float* normb = (const float*)d_in[21];
    const float* fc2w  = (const float*)d_in[22];
    const float* fc2b  = (const float*)d_in[23];
    const float* pcw   = (const float*)d_in[24];
    const float* pcb   = (const float*)d_in[25];
    float* out = (float*)d_out;

    float* p = (float*)d_ws;
    float* h      = p; p += 5120512;     // 10001 x 512
    float* yt     = p; p += 5120512;     // ppeg conv output (channel-major)
    float* ql     = p; p += 131072;
    float* kl     = p; p += 131072;
    float* x2     = p; p += 524288;
    float* scal   = p; p += 32;
    float* part   = p; p += 1081344;     // attn3 partials
    float* ft     = p; p += 5120512;     // ppeg channel-major input
    __hip_bfloat16* qh     = (__hip_bfloat16*)p; p += 2621440;   // [h][NPAD][64]
    __hip_bfloat16* kh     = (__hip_bfloat16*)p; p += 2621440;
    __hip_bfloat16* vh     = (__hip_bfloat16*)p; p += 2621440;
    __hip_bfloat16* xbf    = (__hip_bfloat16*)p; p += 2621440;   // 10240 x 512
    __hip_bfloat16* abf    = (__hip_bfloat16*)p; p += 2588672;   // 10112 x 512
    __hip_bfloat16* convbf = (__hip_bfloat16*)p; p += 2560256;   // 10001 x 512
    __hip_bfloat16* qw1t   = (__hip_bfloat16*)p; p += 393216;
    __hip_bfloat16* qw2t   = (__hip_bfloat16*)p; p += 393216;
    __hip_bfloat16* ow1t   = (__hip_bfloat16*)p; p += 131072;
    __hip_bfloat16* ow2t   = (__hip_bfloat16*)p; p += 131072;
    __hip_bfloat16* x2a    = (__hip_bfloat16*)p; p += 262144;
    __hip_bfloat16* za     = (__hip_bfloat16*)p; p += 262144;
    __hip_bfloat16* zt     = (__hip_bfloat16*)p; p += 262144;
    __hip_bfloat16* za2    = (__hip_bfloat16*)p; p += 262144;
    __hip_bfloat16* zt2    = (__hip_bfloat16*)p; p += 262144;
    __hip_bfloat16* xza    = (__hip_bfloat16*)p; p += 262144;
    __hip_bfloat16* xzt    = (__hip_bfloat16*)p; p += 262144;
    __hip_bfloat16* t1t    = (__hip_bfloat16*)p; p += 262144;
    __hip_bfloat16* t2t    = (__hip_bfloat16*)p; p += 262144;
    __hip_bfloat16* qlbf   = (__hip_bfloat16*)p; p += 65536;
    __hip_bfloat16* klbf   = (__hip_bfloat16*)p; p += 65536;
    __hip_bfloat16* vt     = (__hip_bfloat16*)p; p += 2621440;   // [h][64][NPAD]
    __hip_bfloat16* a3vt   = (__hip_bfloat16*)p; p += 65536;
    __hip_bfloat16* w2bt   = (__hip_bfloat16*)p; p += 65536;

    k_concat<<<dim3((NTOK * DIM + 255) / 256), 256, 0, stream>>>(x, cls, h);
    k_wt_cvt<<<dim3(16, 48), 256, 0, stream>>>(qkv1w, qw1t, 512, 1536);
    k_wt_cvt<<<dim3(16, 48), 256, 0, stream>>>(qkv2w, qw2t, 512, 1536);
    k_wt_cvt<<<dim3(16, 16), 256, 0, stream>>>(out1w, ow1t, 512, 512);
    k_wt_cvt<<<dim3(16, 16), 256, 0, stream>>>(out2w, ow2t, 512, 512);
    k_zerobf<<<dim3((PADR * DIM + 255) / 256), 256, 0, stream>>>(xbf, PADR * DIM);

    auto layer = [&](const float* lnw, const float* lnb, const __hip_bfloat16* qwt,
                     const __hip_bfloat16* owt, const float* outb, const float* resw) {
        k_layernorm_bf<<<NTOK, 256, 0, stream>>>(h, lnw, lnb, xbf);
        // qkv GEMM (global_load_lds staging) -> head-major qh/kh/vh (q pre-scaled 1/8)
        k_qkv_gemm<<<dim3(12, 80), 256, 0, stream>>>(xbf, qwt, qh, kh, vh);
        k_vt<<<dim3(320, 2, HEADS), 256, 0, stream>>>(vh, vt);
        k_landmarks<<<dim3(MLAND, HEADS), 64, 0, stream>>>(qh, kh, ql, kl, qlbf, klbf);
        k_attn2<<<dim3(MLAND, HEADS), 256, 0, stream>>>(ql, kl, x2, x2a);
        k_colrow<<<HEADS, 256, 0, stream>>>(x2, scal);
        k_tscale2<<<dim3(8, 8, HEADS), 256, 0, stream>>>(x2, scal, za, zt);
        // pinv: 24 launch-bound MFMA phases, 64x32 tiles -> 256 blocks (round-17 best)
        {
            __hip_bfloat16 *zra = za, *zrt = zt, *zoa = za2, *zot = zt2;
            dim3 g(8, 4, HEADS);
            for (int it = 0; it < 6; it++) {
                k_mm256<<<g, 256, 0, stream>>>(x2a, zrt, 1.f, 0.f, nullptr, xza, xzt);
                k_mm256<<<g, 256, 0, stream>>>(xza, xzt, -1.f, 7.f, xza, nullptr, t1t);
                k_mm256<<<g, 256, 0, stream>>>(xza, t1t, -1.f, 15.f, xza, nullptr, t2t);
                k_mm256<<<g, 256, 0, stream>>>(zra, t2t, -0.25f, 3.25f, zra, zoa, zot);
                __hip_bfloat16* tmp;
                tmp = zra; zra = zoa; zoa = tmp;
                tmp = zrt; zrt = zot; zot = tmp;
            }
            // final z row-major bf16 ends in za
        }
        // attn3: flash split-N online softmax -> combine (writes a3vt directly)
        k_attn3f<<<dim3(NSPLIT, 4, HEADS), 256, 0, stream>>>(qlbf, kh, vt, part);
        k_a3comb<<<dim3(4, HEADS), 256, 0, stream>>>(part, a3vt);
        // w2b^T = (z @ a3v)^T bf16
        k_mfma_t64<<<dim3(1, 2, HEADS), 256, 0, stream>>>(
            za, 256, 65536, 256, a3vt, 256, 16384,
            w2bt, 256, 16384, 256);
        // conv residual (bf16, x4 vectorized) right before attn1f so convbf is L2-hot
        k_conv_res<<<dim3((NTOK * 128 + 255) / 256), 256, 0, stream>>>(vh, resw, convbf);
        // attn1: fused scores+softmax+P@w2 + convbf add -> abf (bf16)
        k_attn1f<<<dim3(157, HEADS), 256, 0, stream>>>(qh, klbf, w2bt, convbf, abf);
        // out-proj: global_load_lds GEMM, fp32 accumulate into h, +bias
        k_mfma_gemm<<<dim3(4, 79), 256, 0, stream>>>(abf, owt, h, MOUT, 512, 512,
                                                     NTOK, outb, 1);
    };

    layer(ln1w, ln1b, qw1t, ow1t, out1b, res1w);

    k_tfwd<<<dim3(313, 16), 256, 0, stream>>>(h, ft);
    k_ppeg2<<<dim3(5, 512), 256, 0, stream>>>(ft, yt, p7w, p7b, p5w, p5b, p3w, p3b);
    k_tback<<<dim3(313, 16), 256, 0, stream>>>(yt, h);

    layer(ln2w, ln2b, qw2t, ow2t, out2b, res2w);

    k_final<<<NTOK, 256, 0, stream>>>(h, normw, normb, fc2w, fc2b, pcw, pcb, out);
    (void)in_sizes; (void)n_in; (void)out_size; (void)ws_size;
}